// Round 1
// baseline (3439.286 us; speedup 1.0000x reference)
//
#include <hip/hip_runtime.h>
#include <math.h>

#define TPB 256

// Fused Swin block: LN -> window QKV -> 49-token attention -> MLP(+GELU) + residual.
// One block per 7x7 window (8192 windows). All intermediates in LDS.
// LDS layout (floats), phase-reused:
//   [0    .. 4704)  xw (LN'd x, 49x96)   -> scores (49x49=2401) -> hidden tile (49x96)
//   [4704 .. 9408)  q (49x96)            -> attention out "ow" (49x96)
//   [9408 ..14112)  k (49x96)
//   [14112..18816)  v (49x96)
// Total 75,264 B -> 2 blocks/CU.

__global__ __launch_bounds__(TPB, 2) void swin_fused(
    const float* __restrict__ x,
    const float* __restrict__ qkv_w,   // (96, 288)
    const float* __restrict__ ln_w,    // (96)
    const float* __restrict__ ln_b,    // (96)
    const float* __restrict__ w1,      // (96, 384)
    const float* __restrict__ b1,      // (384)
    const float* __restrict__ w2,      // (384, 96)
    const float* __restrict__ b2,      // (96)
    float* __restrict__ out)           // (8,224,224,96)
{
    __shared__ float sA[18816];
    float* xw  = sA;            // 49x96
    float* sq  = sA + 4704;     // 49x96
    float* sk  = sA + 9408;     // 49x96
    float* sv  = sA + 14112;    // 49x96
    float* sc  = sA;            // 49x49 scores (xw dead by then)
    float* sow = sA + 4704;     // attention out (q dead by then)
    float* sh  = sA;            // MLP hidden tile 49x96 (scores dead by then)

    const int tid = threadIdx.x;
    const int win = blockIdx.x;
    const int bb = win >> 10;         // batch
    const int wh = (win >> 5) & 31;   // window row
    const int ww = win & 31;          // window col

    // ---------------- Phase 0: load x window ----------------
    for (int idx = tid; idx < 4704; idx += TPB) {
        int r = idx / 96;
        int c = idx - r * 96;
        int i = r / 7;
        int j = r - i * 7;
        size_t g = ((size_t)((bb * 224 + wh * 7 + i) * 224 + ww * 7 + j)) * 96 + c;
        xw[idx] = x[g];
    }
    __syncthreads();

    // ---------------- Phase 1: LayerNorm (wave per row) ----------------
    {
        const int wave = tid >> 6;
        const int lane = tid & 63;
        const float lw0 = ln_w[lane];
        const float lb0 = ln_b[lane];
        const float lw1 = (lane < 32) ? ln_w[64 + lane] : 0.f;
        const float lb1 = (lane < 32) ? ln_b[64 + lane] : 0.f;
        for (int r = wave; r < 49; r += 4) {
            float v0 = xw[r * 96 + lane];
            float v1 = (lane < 32) ? xw[r * 96 + 64 + lane] : 0.f;
            float s  = v0 + v1;
            float ss = v0 * v0 + v1 * v1;
            #pragma unroll
            for (int o = 32; o > 0; o >>= 1) {
                s  += __shfl_xor(s, o, 64);
                ss += __shfl_xor(ss, o, 64);
            }
            float mean = s * (1.f / 96.f);
            float var  = ss * (1.f / 96.f) - mean * mean;
            float rstd = rsqrtf(var + 1e-5f);
            xw[r * 96 + lane] = (v0 - mean) * rstd * lw0 + lb0;
            if (lane < 32)
                xw[r * 96 + 64 + lane] = (v1 - mean) * rstd * lw1 + lb1;
        }
    }
    __syncthreads();

    // ---------------- Phase 2: QKV GEMM (49x96 @ 96x288) ----------------
    // thread -> (colblock cb of 4 cols, rowgroup rg of 4 rows); 72 colblocks x 3 rowgroups/iter
    {
        const int cb = tid % 72;
        const int rg = tid / 72;   // 0..3 (rg==3 idle)
        const float4* wq4 = (const float4*)qkv_w;
        if (rg < 3) {
            for (int it = 0; it < 5; ++it) {
                int rgg = it * 3 + rg;
                if (rgg >= 13) break;
                int r0 = rgg * 4;
                int ra = min(r0,     48) * 96;
                int rb_ = min(r0 + 1, 48) * 96;
                int rc = min(r0 + 2, 48) * 96;
                int rd = min(r0 + 3, 48) * 96;
                float acc[4][4] = {};
                #pragma unroll 4
                for (int kk = 0; kk < 96; ++kk) {
                    float4 wv = wq4[kk * 72 + cb];
                    float x0 = xw[ra + kk];
                    float x1 = xw[rb_ + kk];
                    float x2 = xw[rc + kk];
                    float x3 = xw[rd + kk];
                    acc[0][0] += x0 * wv.x; acc[0][1] += x0 * wv.y; acc[0][2] += x0 * wv.z; acc[0][3] += x0 * wv.w;
                    acc[1][0] += x1 * wv.x; acc[1][1] += x1 * wv.y; acc[1][2] += x1 * wv.z; acc[1][3] += x1 * wv.w;
                    acc[2][0] += x2 * wv.x; acc[2][1] += x2 * wv.y; acc[2][2] += x2 * wv.z; acc[2][3] += x2 * wv.w;
                    acc[3][0] += x3 * wv.x; acc[3][1] += x3 * wv.y; acc[3][2] += x3 * wv.z; acc[3][3] += x3 * wv.w;
                }
                int c0 = cb * 4;
                int sec = c0 / 96;
                int lc = c0 - sec * 96;
                float* dst = (sec == 0) ? sq : (sec == 1) ? sk : sv;
                #pragma unroll
                for (int i = 0; i < 4; ++i) {
                    int r = r0 + i;
                    if (r < 49) {
                        float4 o4; o4.x = acc[i][0]; o4.y = acc[i][1]; o4.z = acc[i][2]; o4.w = acc[i][3];
                        *(float4*)&dst[r * 96 + lc] = o4;
                    }
                }
            }
        }
    }
    __syncthreads();

    // ---------------- Phase 3: scores = Q K^T / sqrt(96) (49x49) ----------------
    if (tid < 169) {
        const int mb = tid % 13;
        const int nb = tid / 13;
        const int n0 = nb * 4, m0 = mb * 4;
        int ni[4], mi[4];
        #pragma unroll
        for (int i = 0; i < 4; ++i) { ni[i] = min(n0 + i, 48) * 96; mi[i] = min(m0 + i, 48) * 96; }
        float acc[4][4] = {};
        for (int c4 = 0; c4 < 96; c4 += 4) {
            float4 qv[4], kv[4];
            #pragma unroll
            for (int i = 0; i < 4; ++i) qv[i] = *(const float4*)&sq[ni[i] + c4];
            #pragma unroll
            for (int j = 0; j < 4; ++j) kv[j] = *(const float4*)&sk[mi[j] + c4];
            #pragma unroll
            for (int i = 0; i < 4; ++i)
                #pragma unroll
                for (int j = 0; j < 4; ++j)
                    acc[i][j] += qv[i].x * kv[j].x + qv[i].y * kv[j].y + qv[i].z * kv[j].z + qv[i].w * kv[j].w;
        }
        const float rs = 0.10206207261596575f; // 1/sqrt(96)
        #pragma unroll
        for (int i = 0; i < 4; ++i) {
            int n = n0 + i;
            if (n < 49) {
                #pragma unroll
                for (int j = 0; j < 4; ++j) {
                    int m = m0 + j;
                    if (m < 49) sc[n * 49 + m] = acc[i][j] * rs;
                }
            }
        }
    }
    __syncthreads();

    // ---------------- Phase 4: softmax rows (wave per row) ----------------
    {
        const int wave = tid >> 6;
        const int lane = tid & 63;
        for (int r = wave; r < 49; r += 4) {
            float v = (lane < 49) ? sc[r * 49 + lane] : -INFINITY;
            float mx = v;
            #pragma unroll
            for (int o = 32; o > 0; o >>= 1) mx = fmaxf(mx, __shfl_xor(mx, o, 64));
            float e = (lane < 49) ? expf(v - mx) : 0.f;
            float s = e;
            #pragma unroll
            for (int o = 32; o > 0; o >>= 1) s += __shfl_xor(s, o, 64);
            if (lane < 49) sc[r * 49 + lane] = e / s;
        }
    }
    __syncthreads();

    // ---------------- Phase 5: ow = P @ V (49x96) ----------------
    #pragma unroll
    for (int ii = 0; ii < 2; ++ii) {
        int idx = tid + ii * TPB;
        if (idx < 312) {
            int cb = idx % 24, rb = idx / 24;
            int c0 = cb * 4, r0 = rb * 4;
            int ri[4];
            #pragma unroll
            for (int i = 0; i < 4; ++i) ri[i] = min(r0 + i, 48) * 49;
            float acc[4][4] = {};
            for (int m = 0; m < 49; ++m) {
                float4 vv = *(const float4*)&sv[m * 96 + c0];
                #pragma unroll
                for (int i = 0; i < 4; ++i) {
                    float p = sc[ri[i] + m];
                    acc[i][0] += p * vv.x; acc[i][1] += p * vv.y; acc[i][2] += p * vv.z; acc[i][3] += p * vv.w;
                }
            }
            #pragma unroll
            for (int i = 0; i < 4; ++i) {
                int r = r0 + i;
                if (r < 49) {
                    float4 o4; o4.x = acc[i][0]; o4.y = acc[i][1]; o4.z = acc[i][2]; o4.w = acc[i][3];
                    *(float4*)&sow[r * 96 + c0] = o4;
                }
            }
        }
    }
    __syncthreads();

    // ---------------- Phase 6: MLP in 4 column tiles of 96, y accumulated in regs ----------------
    float yacc[2][4][4] = {};
    for (int t = 0; t < 4; ++t) {
        // hidden tile: sh = gelu(ow @ w1[:, t*96:(t+1)*96] + b1)
        #pragma unroll
        for (int ii = 0; ii < 2; ++ii) {
            int idx = tid + ii * TPB;
            if (idx < 312) {
                int cb = idx % 24, rb = idx / 24;
                int c0 = cb * 4, r0 = rb * 4;
                int ri[4];
                #pragma unroll
                for (int i = 0; i < 4; ++i) ri[i] = min(r0 + i, 48) * 96;
                float acc[4][4] = {};
                const float4* w14 = (const float4*)w1;
                #pragma unroll 4
                for (int kk = 0; kk < 96; ++kk) {
                    float4 wv = w14[kk * 96 + t * 24 + cb];
                    #pragma unroll
                    for (int i = 0; i < 4; ++i) {
                        float o = sow[ri[i] + kk];
                        acc[i][0] += o * wv.x; acc[i][1] += o * wv.y; acc[i][2] += o * wv.z; acc[i][3] += o * wv.w;
                    }
                }
                float4 bv = *(const float4*)&b1[t * 96 + c0];
                #pragma unroll
                for (int i = 0; i < 4; ++i) {
                    int r = r0 + i;
                    if (r < 49) {
                        float h0 = acc[i][0] + bv.x, h1 = acc[i][1] + bv.y, h2 = acc[i][2] + bv.z, h3 = acc[i][3] + bv.w;
                        float4 g4;
                        g4.x = 0.5f * h0 * (1.f + erff(h0 * 0.70710678118654752f));
                        g4.y = 0.5f * h1 * (1.f + erff(h1 * 0.70710678118654752f));
                        g4.z = 0.5f * h2 * (1.f + erff(h2 * 0.70710678118654752f));
                        g4.w = 0.5f * h3 * (1.f + erff(h3 * 0.70710678118654752f));
                        *(float4*)&sh[r * 96 + c0] = g4;
                    }
                }
            }
        }
        __syncthreads();
        // y += sh @ w2[t*96:(t+1)*96, :]
        #pragma unroll
        for (int ii = 0; ii < 2; ++ii) {
            int idx = tid + ii * TPB;
            if (idx < 312) {
                int cb = idx % 24, rb = idx / 24;
                int r0 = rb * 4;
                int ri[4];
                #pragma unroll
                for (int i = 0; i < 4; ++i) ri[i] = min(r0 + i, 48) * 96;
                const float4* w24 = (const float4*)w2;
                #pragma unroll 4
                for (int kk = 0; kk < 96; ++kk) {
                    float4 wv = w24[(t * 96 + kk) * 24 + cb];
                    #pragma unroll
                    for (int i = 0; i < 4; ++i) {
                        float h = sh[ri[i] + kk];
                        yacc[ii][i][0] += h * wv.x; yacc[ii][i][1] += h * wv.y;
                        yacc[ii][i][2] += h * wv.z; yacc[ii][i][3] += h * wv.w;
                    }
                }
            }
        }
        __syncthreads();
    }

    // ---------------- Epilogue: out = y + b2 + ow ----------------
    #pragma unroll
    for (int ii = 0; ii < 2; ++ii) {
        int idx = tid + ii * TPB;
        if (idx < 312) {
            int cb = idx % 24, rb = idx / 24;
            int c0 = cb * 4, r0 = rb * 4;
            float4 b2v = *(const float4*)&b2[c0];
            #pragma unroll
            for (int i = 0; i < 4; ++i) {
                int r = r0 + i;
                if (r < 49) {
                    int pi = r / 7, pj = r - (r / 7) * 7;
                    size_t g = ((size_t)((bb * 224 + wh * 7 + pi) * 224 + ww * 7 + pj)) * 96 + c0;
                    float4 ov = *(const float4*)&sow[r * 96 + c0];
                    float4 res;
                    res.x = yacc[ii][i][0] + b2v.x + ov.x;
                    res.y = yacc[ii][i][1] + b2v.y + ov.y;
                    res.z = yacc[ii][i][2] + b2v.z + ov.z;
                    res.w = yacc[ii][i][3] + b2v.w + ov.w;
                    *(float4*)&out[g] = res;
                }
            }
        }
    }
}

extern "C" void kernel_launch(void* const* d_in, const int* in_sizes, int n_in,
                              void* d_out, int out_size, void* d_ws, size_t ws_size,
                              hipStream_t stream) {
    const float* x     = (const float*)d_in[0];
    const float* qkv_w = (const float*)d_in[1];
    const float* ln_w  = (const float*)d_in[2];
    const float* ln_b  = (const float*)d_in[3];
    const float* w1    = (const float*)d_in[4];
    const float* b1    = (const float*)d_in[5];
    const float* w2    = (const float*)d_in[6];
    const float* b2    = (const float*)d_in[7];
    float* out = (float*)d_out;

    swin_fused<<<8192, TPB, 0, stream>>>(x, qkv_w, ln_w, ln_b, w1, b1, w2, b2, out);
}

// Round 2
// 608.432 us; speedup vs baseline: 5.6527x; 5.6527x over previous
//
#include <hip/hip_runtime.h>
#include <math.h>

typedef __attribute__((ext_vector_type(8))) short short8;
typedef __attribute__((ext_vector_type(4))) float float4v;

__device__ __forceinline__ short f2bf(float f) {
    unsigned u = __float_as_uint(f);
    u = (u + 0x7FFFu + ((u >> 16) & 1u)) >> 16;
    return (short)u;
}
__device__ __forceinline__ float gelu_f(float x) {
    // tanh approximation of gelu: max abs dev vs erf form ~1e-3 (threshold 6.6e-2)
    float u = 1.5957691216057308f * (x + 0.044715f * x * x * x); // 2*sqrt(2/pi)*(...)
    float e = __expf(u);
    float t = 1.f - 2.f / (e + 1.f);   // tanh(u/… ) safe at +-inf
    return 0.5f * x * (1.f + t);
}

// ---------------- weight conversion: fp32 -> bf16 in B-fragment order ----------------
// B-frag layout for mfma_f32_16x16x32_bf16: lane l holds B[k = kc*32 + (l>>4)*8 + j][n = t*16 + (l&15)]
// ws layout (shorts): [0,27648) qkv_w  (18 tiles x 3 kc x 64 lanes x 8)
//                     [27648,64512) w1 (24 tiles x 3 kc)
//                     [64512,101376) w2 ([tn 0..5][kcg 0..11])
__global__ void convert_weights(const float* __restrict__ qkv_w,
                                const float* __restrict__ w1,
                                const float* __restrict__ w2,
                                short* __restrict__ ws) {
    int e = blockIdx.x * 256 + threadIdx.x;
    if (e >= 101376) return;
    if (e < 27648) {
        int f = e >> 3, j = e & 7;
        int lane = f & 63, fc = f >> 6;
        int kc = fc % 3, t = fc / 3;
        int k = kc * 32 + ((lane >> 4) << 3) + j;
        int col = t * 16 + (lane & 15);
        ws[e] = f2bf(qkv_w[k * 288 + col]);
    } else if (e < 64512) {
        int e2 = e - 27648;
        int f = e2 >> 3, j = e2 & 7;
        int lane = f & 63, fc = f >> 6;
        int kc = fc % 3, t = fc / 3;
        int k = kc * 32 + ((lane >> 4) << 3) + j;
        int col = t * 16 + (lane & 15);
        ws[27648 + e2] = f2bf(w1[k * 384 + col]);
    } else {
        int e3 = e - 64512;
        int f = e3 >> 3, j = e3 & 7;
        int lane = f & 63, fc = f >> 6;
        int kcg = fc % 12, tn = fc / 12;
        int k = kcg * 32 + ((lane >> 4) << 3) + j;
        int col = tn * 16 + (lane & 15);
        ws[64512 + e3] = f2bf(w2[k * 96 + col]);
    }
}

// ---------------- fused swin block, bf16 MFMA ----------------
// One block per 7x7 window. 4 waves, wave w owns token rows 16w..16w+15 (rows 49..63 zero pad).
// LDS (shorts): XA 64x104 @0, Q/O 64x104 @6656, K 64x104 @13312, P 64x72 @19968, VB frag @24576
#define XA_ 0
#define Q_  6656
#define K_  13312
#define P_  19968
#define VB_ 24576

__global__ __launch_bounds__(256, 2) void swin_mfma(
    const float* __restrict__ x,
    const float* __restrict__ ln_w, const float* __restrict__ ln_b,
    const float* __restrict__ b1,   const float* __restrict__ b2,
    const short* __restrict__ ws,
    float* __restrict__ out)
{
    __shared__ __align__(16) short lds[30720];
    const short* wsQKV = ws;
    const short* wsW1  = ws + 27648;
    const short* wsW2  = ws + 64512;

    const int tid = threadIdx.x;
    const int w = tid >> 6, lane = tid & 63, q = lane >> 4, n16 = lane & 15;
    const int win = blockIdx.x;
    const int bb = win >> 10, wh = (win >> 5) & 31, ww = win & 31;
    const int rowb = w * 16 + q * 4;            // C/D-layout row base for this lane

    // ---------- Phase A: load x, LayerNorm, bf16 -> XA (row-major, stride 104) ----------
    {
        int r = w * 16 + n16;                   // this lane's token row (frag layout role)
        float v[24];
        if (r < 49) {
            int i = r / 7, jj = r - i * 7;
            const float* xp = x + ((size_t)((bb * 224 + wh * 7 + i) * 224 + ww * 7 + jj)) * 96 + q * 8;
            #pragma unroll
            for (int kc = 0; kc < 3; ++kc) {
                float4 u0 = *(const float4*)(xp + kc * 32);
                float4 u1 = *(const float4*)(xp + kc * 32 + 4);
                v[kc*8+0] = u0.x; v[kc*8+1] = u0.y; v[kc*8+2] = u0.z; v[kc*8+3] = u0.w;
                v[kc*8+4] = u1.x; v[kc*8+5] = u1.y; v[kc*8+6] = u1.z; v[kc*8+7] = u1.w;
            }
        } else {
            #pragma unroll
            for (int c = 0; c < 24; ++c) v[c] = 0.f;
        }
        float s = 0.f, ss = 0.f;
        #pragma unroll
        for (int c = 0; c < 24; ++c) { s += v[c]; ss += v[c] * v[c]; }
        s  += __shfl_xor(s, 16);  s  += __shfl_xor(s, 32);   // combine the 4 quads of this row
        ss += __shfl_xor(ss, 16); ss += __shfl_xor(ss, 32);
        float mean = s * (1.f / 96.f);
        float var  = ss * (1.f / 96.f) - mean * mean;
        float rstd = rsqrtf(var + 1e-5f);
        #pragma unroll
        for (int kc = 0; kc < 3; ++kc) {
            short8 o;
            #pragma unroll
            for (int j = 0; j < 8; ++j) {
                int c = kc * 32 + q * 8 + j;
                float xn = (r < 49) ? ((v[kc*8+j] - mean) * rstd * ln_w[c] + ln_b[c]) : 0.f;
                o[j] = f2bf(xn);
            }
            *(short8*)&lds[XA_ + r * 104 + kc * 32 + q * 8] = o;
        }
    }
    // same-wave LDS write->read (DS ops are in-order per wave): no barrier needed

    // ---------- Phase B: QKV = XA @ qkv_w (18 n-tiles, K=96) ----------
    {
        short8 af[3];
        #pragma unroll
        for (int kc = 0; kc < 3; ++kc)
            af[kc] = *(const short8*)&lds[XA_ + (w * 16 + n16) * 104 + kc * 32 + q * 8];

        #pragma unroll
        for (int tp = 0; tp < 9; ++tp) {
            int t0 = tp * 2, t1 = t0 + 1;
            float4v a0 = {0.f, 0.f, 0.f, 0.f}, a1 = {0.f, 0.f, 0.f, 0.f};
            #pragma unroll
            for (int kc = 0; kc < 3; ++kc) {
                short8 bf0 = *(const short8*)(wsQKV + ((t0 * 3 + kc) * 64 + lane) * 8);
                short8 bf1 = *(const short8*)(wsQKV + ((t1 * 3 + kc) * 64 + lane) * 8);
                a0 = __builtin_amdgcn_mfma_f32_16x16x32_bf16(af[kc], bf0, a0, 0, 0, 0);
                a1 = __builtin_amdgcn_mfma_f32_16x16x32_bf16(af[kc], bf1, a1, 0, 0, 0);
            }
            #pragma unroll
            for (int hh = 0; hh < 2; ++hh) {
                int t = hh ? t1 : t0;
                float4v a = hh ? a1 : a0;
                if (t < 12) {
                    int base = (t < 6 ? Q_ : K_) + (t % 6) * 16 + n16;
                    #pragma unroll
                    for (int rg = 0; rg < 4; ++rg)
                        lds[base + (rowb + rg) * 104] = f2bf(a[rg]);
                } else {
                    int tV = t - 12;
                    #pragma unroll
                    for (int rg = 0; rg < 4; ++rg) {
                        int row = rowb + rg;
                        lds[VB_ + (((tV * 2 + (row >> 5)) * 64 + ((row >> 3) & 3) * 16 + n16) << 3) + (row & 7)]
                            = f2bf(a[rg]);
                    }
                }
            }
        }
    }
    __syncthreads();   // the ONLY barrier: K and VB are read cross-wave below

    // ---------- Phase C: S = Q K^T / sqrt(96), softmax -> P (bf16, stride 72) ----------
    {
        short8 qf[3];
        #pragma unroll
        for (int kc = 0; kc < 3; ++kc)
            qf[kc] = *(const short8*)&lds[Q_ + (w * 16 + n16) * 104 + kc * 32 + q * 8];
        float4v sv[4];
        #pragma unroll
        for (int tn = 0; tn < 4; ++tn) sv[tn] = (float4v){0.f, 0.f, 0.f, 0.f};
        #pragma unroll
        for (int kc = 0; kc < 3; ++kc) {
            #pragma unroll
            for (int tn = 0; tn < 4; ++tn) {
                short8 kf = *(const short8*)&lds[K_ + (tn * 16 + n16) * 104 + kc * 32 + q * 8];
                sv[tn] = __builtin_amdgcn_mfma_f32_16x16x32_bf16(qf[kc], kf, sv[tn], 0, 0, 0);
            }
        }
        const float rs = 0.10206207261596575f;
        #pragma unroll
        for (int rg = 0; rg < 4; ++rg) {
            float v0 = sv[0][rg] * rs;
            float v1 = sv[1][rg] * rs;
            float v2 = sv[2][rg] * rs;
            float v3 = (n16 == 0) ? sv[3][rg] * rs : -1e30f;   // mask cols 49..63
            float mx = fmaxf(fmaxf(v0, v1), fmaxf(v2, v3));
            #pragma unroll
            for (int o = 1; o < 16; o <<= 1) mx = fmaxf(mx, __shfl_xor(mx, o));
            float e0 = __expf(v0 - mx), e1 = __expf(v1 - mx);
            float e2 = __expf(v2 - mx), e3 = __expf(v3 - mx);
            float sum = e0 + e1 + e2 + e3;
            #pragma unroll
            for (int o = 1; o < 16; o <<= 1) sum += __shfl_xor(sum, o);
            float inv = 1.f / sum;
            int pr = P_ + (rowb + rg) * 72 + n16;
            lds[pr +  0] = f2bf(e0 * inv);
            lds[pr + 16] = f2bf(e1 * inv);
            lds[pr + 32] = f2bf(e2 * inv);
            lds[pr + 48] = f2bf(e3 * inv);
        }
    }

    // ---------- Phase D: O = P @ V (write bf16 O over Q buffer; keep fp32 O for residual) ----------
    float4v ov[6];
    {
        short8 pf0 = *(const short8*)&lds[P_ + (w * 16 + n16) * 72 + q * 8];
        short8 pf1 = *(const short8*)&lds[P_ + (w * 16 + n16) * 72 + 32 + q * 8];
        #pragma unroll
        for (int tV = 0; tV < 6; ++tV) {
            float4v a = {0.f, 0.f, 0.f, 0.f};
            short8 vf0 = *(const short8*)&lds[VB_ + ((tV * 2 + 0) * 64 + lane) * 8];
            short8 vf1 = *(const short8*)&lds[VB_ + ((tV * 2 + 1) * 64 + lane) * 8];
            a = __builtin_amdgcn_mfma_f32_16x16x32_bf16(pf0, vf0, a, 0, 0, 0);
            a = __builtin_amdgcn_mfma_f32_16x16x32_bf16(pf1, vf1, a, 0, 0, 0);
            ov[tV] = a;
            #pragma unroll
            for (int rg = 0; rg < 4; ++rg)
                lds[Q_ + (rowb + rg) * 104 + tV * 16 + n16] = f2bf(a[rg]);
        }
    }

    // ---------- Phase E: MLP, 4 column tiles of 96; y accumulated in regs ----------
    float4v y[6];
    #pragma unroll
    for (int tn = 0; tn < 6; ++tn) y[tn] = (float4v){0.f, 0.f, 0.f, 0.f};
    {
        short8 of[3];
        #pragma unroll
        for (int kc = 0; kc < 3; ++kc)
            of[kc] = *(const short8*)&lds[Q_ + (w * 16 + n16) * 104 + kc * 32 + q * 8];

        for (int t = 0; t < 4; ++t) {
            // H = gelu(O @ W1[:, t*96 .. t*96+95] + b1) -> XA buffer
            #pragma unroll
            for (int tp = 0; tp < 3; ++tp) {
                int tn0 = tp * 2, tn1 = tn0 + 1;
                float4v h0 = {0.f, 0.f, 0.f, 0.f}, h1 = {0.f, 0.f, 0.f, 0.f};
                #pragma unroll
                for (int kc = 0; kc < 3; ++kc) {
                    short8 wf0 = *(const short8*)(wsW1 + (((t * 6 + tn0) * 3 + kc) * 64 + lane) * 8);
                    short8 wf1 = *(const short8*)(wsW1 + (((t * 6 + tn1) * 3 + kc) * 64 + lane) * 8);
                    h0 = __builtin_amdgcn_mfma_f32_16x16x32_bf16(of[kc], wf0, h0, 0, 0, 0);
                    h1 = __builtin_amdgcn_mfma_f32_16x16x32_bf16(of[kc], wf1, h1, 0, 0, 0);
                }
                float bb0 = b1[t * 96 + tn0 * 16 + n16];
                float bb1v = b1[t * 96 + tn1 * 16 + n16];
                #pragma unroll
                for (int rg = 0; rg < 4; ++rg) {
                    lds[XA_ + (rowb + rg) * 104 + tn0 * 16 + n16] = f2bf(gelu_f(h0[rg] + bb0));
                    lds[XA_ + (rowb + rg) * 104 + tn1 * 16 + n16] = f2bf(gelu_f(h1[rg] + bb1v));
                }
            }
            // y += H @ W2[t*96 .. t*96+95, :]   (same-wave LDS dependency, no barrier)
            short8 hf[3];
            #pragma unroll
            for (int kc = 0; kc < 3; ++kc)
                hf[kc] = *(const short8*)&lds[XA_ + (w * 16 + n16) * 104 + kc * 32 + q * 8];
            #pragma unroll
            for (int tp = 0; tp < 3; ++tp) {
                int tn0 = tp * 2, tn1 = tn0 + 1;
                #pragma unroll
                for (int kc = 0; kc < 3; ++kc) {
                    short8 wf0 = *(const short8*)(wsW2 + ((tn0 * 12 + t * 3 + kc) * 64 + lane) * 8);
                    short8 wf1 = *(const short8*)(wsW2 + ((tn1 * 12 + t * 3 + kc) * 64 + lane) * 8);
                    y[tn0] = __builtin_amdgcn_mfma_f32_16x16x32_bf16(hf[kc], wf0, y[tn0], 0, 0, 0);
                    y[tn1] = __builtin_amdgcn_mfma_f32_16x16x32_bf16(hf[kc], wf1, y[tn1], 0, 0, 0);
                }
            }
        }
    }

    // ---------- Epilogue: out = y + b2 + O(fp32 regs) ----------
    #pragma unroll
    for (int rg = 0; rg < 4; ++rg) {
        int r = rowb + rg;
        if (r < 49) {
            int i = r / 7, jj = r - i * 7;
            float* op = out + ((size_t)((bb * 224 + wh * 7 + i) * 224 + ww * 7 + jj)) * 96 + n16;
            #pragma unroll
            for (int tn = 0; tn < 6; ++tn)
                op[tn * 16] = y[tn][rg] + b2[tn * 16 + n16] + ov[tn][rg];
        }
    }
}

extern "C" void kernel_launch(void* const* d_in, const int* in_sizes, int n_in,
                              void* d_out, int out_size, void* d_ws, size_t ws_size,
                              hipStream_t stream) {
    const float* x     = (const float*)d_in[0];
    const float* qkv_w = (const float*)d_in[1];
    const float* ln_w  = (const float*)d_in[2];
    const float* ln_b  = (const float*)d_in[3];
    const float* w1    = (const float*)d_in[4];
    const float* b1    = (const float*)d_in[5];
    const float* w2    = (const float*)d_in[6];
    const float* b2    = (const float*)d_in[7];
    float* out = (float*)d_out;
    short* ws = (short*)d_ws;

    convert_weights<<<396, 256, 0, stream>>>(qkv_w, w1, w2, ws);
    swin_mfma<<<8192, 256, 0, stream>>>(x, ln_w, ln_b, b1, b2, ws, out);
}

// Round 3
// 446.248 us; speedup vs baseline: 7.7071x; 1.3634x over previous
//
#include <hip/hip_runtime.h>
#include <math.h>

typedef __attribute__((ext_vector_type(8))) short short8;
typedef __attribute__((ext_vector_type(4))) float float4v;

// round-half-up f32->bf16 (max 0.5 ulp, ties up): 2 instrs
__device__ __forceinline__ short f2bf(float f) {
    return (short)((__float_as_uint(f) + 0x8000u) >> 16);
}
// sigmoid-approx gelu: x * sigmoid(1.702x); 1.702*log2(e) = 2.4554542
__device__ __forceinline__ float gelu_sig(float x) {
    return x * __builtin_amdgcn_rcpf(1.f + __builtin_amdgcn_exp2f(-2.4554542f * x));
}
__device__ __forceinline__ void stage16(const short* g, short* l) {
    __builtin_amdgcn_global_load_lds(
        (__attribute__((address_space(1))) void*)g,
        (__attribute__((address_space(3))) void*)l, 16, 0, 0);
}

// ---------------- weight conversion: fp32 -> bf16 in B-fragment order ----------------
// B-frag (mfma 16x16x32 bf16): lane l holds B[k = kc*32 + (l>>4)*8 + j][n = tile*16 + (l&15)]
// ws (shorts): [0,27648) qkv_w  [(tile 0..17)*3+kc]
//              [27648,64512) w1 [(t*6+tn)*3+kc]            (t-slice = 9216 contiguous)
//              [64512,101376) w2 [(t*6+tn)*3+kc], k-rows t*96+kc*32.. (t-slice contiguous)
__global__ void convert_weights(const float* __restrict__ qkv_w,
                                const float* __restrict__ w1,
                                const float* __restrict__ w2,
                                short* __restrict__ ws) {
    int e = blockIdx.x * 256 + threadIdx.x;
    if (e >= 101376) return;
    if (e < 27648) {
        int j = e & 7, lane = (e >> 3) & 63, fc = e >> 9;
        int kc = fc % 3, t = fc / 3;
        int k = kc * 32 + ((lane >> 4) << 3) + j;
        int col = t * 16 + (lane & 15);
        ws[e] = f2bf(qkv_w[k * 288 + col]);
    } else if (e < 64512) {
        int e2 = e - 27648;
        int j = e2 & 7, lane = (e2 >> 3) & 63, fc = e2 >> 9;
        int kc = fc % 3, tile = fc / 3;             // tile = t*6+tn
        int k = kc * 32 + ((lane >> 4) << 3) + j;
        int col = tile * 16 + (lane & 15);          // = t*96 + tn*16 + (lane&15)... col in [0,384)
        ws[27648 + e2] = f2bf(w1[k * 384 + col]);
    } else {
        int e3 = e - 64512;
        int j = e3 & 7, lane = (e3 >> 3) & 63, fc = e3 >> 9;
        int kc = fc % 3, tn = (fc / 3) % 6, t = fc / 18;
        int k = t * 96 + kc * 32 + ((lane >> 4) << 3) + j;
        int col = tn * 16 + (lane & 15);
        ws[64512 + e3] = f2bf(w2[k * 96 + col]);
    }
}

// ---------------- fused swin block ----------------
// One block per 7x7 window, 4 waves. LDS (shorts), total 26112 (52224 B -> 3 blocks/CU):
//   XA_ [0,6656)      LN'd x rows (stride 104) -> P (softmax, stride 72) -> H (MLP hidden)
//   Q_  [6656,13312)  Q rows -> O rows (bf16)
//   K_  [13312,19968) K rows;  WS_ weight stage [13312,22528) reuses K+part of VB in phase E
//   VB_ [19968,26112) V in B-frag layout
#define XA_ 0
#define Q_  6656
#define K_  13312
#define VB_ 19968
#define WS_ 13312

__global__ __launch_bounds__(256, 3) void swin_mfma(
    const float* __restrict__ x,
    const float* __restrict__ ln_w, const float* __restrict__ ln_b,
    const float* __restrict__ b1,   const float* __restrict__ b2,
    const short* __restrict__ ws,
    float* __restrict__ out)
{
    __shared__ __align__(16) short lds[26112];
    const short* wsQKV = ws;
    const short* wsW1  = ws + 27648;
    const short* wsW2  = ws + 64512;

    const int tid = threadIdx.x;
    const int w = tid >> 6, lane = tid & 63, q = lane >> 4, n16 = lane & 15;
    const int win = blockIdx.x;
    const int bb = win >> 10, wh = (win >> 5) & 31, ww = win & 31;
    const int rowb = w * 16 + q * 4;          // C/D-layout row base

    // ---------- Phase A: load x, LayerNorm, bf16 -> XA ----------
    {
        int r = w * 16 + n16;
        float v[24];
        if (r < 49) {
            int i = r / 7, jj = r - i * 7;
            const float* xp = x + ((size_t)((bb * 224 + wh * 7 + i) * 224 + ww * 7 + jj)) * 96 + q * 8;
            #pragma unroll
            for (int kc = 0; kc < 3; ++kc) {
                float4 u0 = *(const float4*)(xp + kc * 32);
                float4 u1 = *(const float4*)(xp + kc * 32 + 4);
                v[kc*8+0] = u0.x; v[kc*8+1] = u0.y; v[kc*8+2] = u0.z; v[kc*8+3] = u0.w;
                v[kc*8+4] = u1.x; v[kc*8+5] = u1.y; v[kc*8+6] = u1.z; v[kc*8+7] = u1.w;
            }
        } else {
            #pragma unroll
            for (int c = 0; c < 24; ++c) v[c] = 0.f;
        }
        float s = 0.f, ss = 0.f;
        #pragma unroll
        for (int c = 0; c < 24; ++c) { s += v[c]; ss += v[c] * v[c]; }
        s  += __shfl_xor(s, 16);  s  += __shfl_xor(s, 32);
        ss += __shfl_xor(ss, 16); ss += __shfl_xor(ss, 32);
        float mean = s * (1.f / 96.f);
        float var  = ss * (1.f / 96.f) - mean * mean;
        float rstd = rsqrtf(var + 1e-5f);
        #pragma unroll
        for (int kc = 0; kc < 3; ++kc) {
            short8 o;
            #pragma unroll
            for (int j = 0; j < 8; ++j) {
                int c = kc * 32 + q * 8 + j;
                float xn = (r < 49) ? ((v[kc*8+j] - mean) * rstd * ln_w[c] + ln_b[c]) : 0.f;
                o[j] = f2bf(xn);
            }
            *(short8*)&lds[XA_ + r * 104 + kc * 32 + q * 8] = o;
        }
    }
    __syncthreads();   // XA read cross-wave in N-split phase B

    // ---------- Phase B: QKV, N-split across waves (weights fetched once/window) ----------
    {
        short8 af[4][3];
        #pragma unroll
        for (int M = 0; M < 4; ++M)
            #pragma unroll
            for (int kc = 0; kc < 3; ++kc)
                af[M][kc] = *(const short8*)&lds[XA_ + (M * 16 + n16) * 104 + kc * 32 + q * 8];

        for (int n = w; n < 18; n += 4) {
            float4v c[4];
            #pragma unroll
            for (int M = 0; M < 4; ++M) c[M] = (float4v){0.f, 0.f, 0.f, 0.f};
            #pragma unroll
            for (int kc = 0; kc < 3; ++kc) {
                short8 bf = *(const short8*)(wsQKV + ((n * 3 + kc) * 64 + lane) * 8);
                #pragma unroll
                for (int M = 0; M < 4; ++M)
                    c[M] = __builtin_amdgcn_mfma_f32_16x16x32_bf16(af[M][kc], bf, c[M], 0, 0, 0);
            }
            if (n < 12) {
                int base = (n < 6 ? Q_ + n * 16 : K_ + (n - 6) * 16) + n16;
                #pragma unroll
                for (int M = 0; M < 4; ++M)
                    #pragma unroll
                    for (int rg = 0; rg < 4; ++rg)
                        lds[base + (M * 16 + q * 4 + rg) * 104] = f2bf(c[M][rg]);
            } else {
                int tV = n - 12;
                #pragma unroll
                for (int M = 0; M < 4; ++M)
                    #pragma unroll
                    for (int rg = 0; rg < 4; ++rg) {
                        int row = M * 16 + q * 4 + rg;
                        lds[VB_ + (((tV * 2 + (row >> 5)) * 64 + ((row >> 3) & 3) * 16 + n16) << 3) + (row & 7)]
                            = f2bf(c[M][rg]);
                    }
            }
        }
    }
    __syncthreads();   // Q/K/VB complete

    // ---------- Phase C: S = Q K^T / sqrt(96), softmax -> P (stride 72, in XA region) ----------
    {
        short8 qf[3];
        #pragma unroll
        for (int kc = 0; kc < 3; ++kc)
            qf[kc] = *(const short8*)&lds[Q_ + (w * 16 + n16) * 104 + kc * 32 + q * 8];
        float4v sv[4];
        #pragma unroll
        for (int tn = 0; tn < 4; ++tn) sv[tn] = (float4v){0.f, 0.f, 0.f, 0.f};
        #pragma unroll
        for (int kc = 0; kc < 3; ++kc)
            #pragma unroll
            for (int tn = 0; tn < 4; ++tn) {
                short8 kf = *(const short8*)&lds[K_ + (tn * 16 + n16) * 104 + kc * 32 + q * 8];
                sv[tn] = __builtin_amdgcn_mfma_f32_16x16x32_bf16(qf[kc], kf, sv[tn], 0, 0, 0);
            }
        const float rs = 0.10206207261596575f;
        #pragma unroll
        for (int rg = 0; rg < 4; ++rg) {
            float v0 = sv[0][rg] * rs;
            float v1 = sv[1][rg] * rs;
            float v2 = sv[2][rg] * rs;
            float v3 = (n16 == 0) ? sv[3][rg] * rs : -1e30f;
            float mx = fmaxf(fmaxf(v0, v1), fmaxf(v2, v3));
            #pragma unroll
            for (int o = 1; o < 16; o <<= 1) mx = fmaxf(mx, __shfl_xor(mx, o));
            float e0 = __expf(v0 - mx), e1 = __expf(v1 - mx);
            float e2 = __expf(v2 - mx), e3 = __expf(v3 - mx);
            float sum = e0 + e1 + e2 + e3;
            #pragma unroll
            for (int o = 1; o < 16; o <<= 1) sum += __shfl_xor(sum, o);
            float inv = __builtin_amdgcn_rcpf(sum);
            int pr = XA_ + (rowb + rg) * 72 + n16;
            lds[pr +  0] = f2bf(e0 * inv);
            lds[pr + 16] = f2bf(e1 * inv);
            lds[pr + 32] = f2bf(e2 * inv);
            lds[pr + 48] = f2bf(e3 * inv);
        }
    }

    // ---------- Phase D: O = P @ V (own rows; bf16 O over Q buffer; fp32 O in regs) ----------
    float4v ov[6];
    {
        short8 pf0 = *(const short8*)&lds[XA_ + (w * 16 + n16) * 72 + q * 8];
        short8 pf1 = *(const short8*)&lds[XA_ + (w * 16 + n16) * 72 + 32 + q * 8];
        #pragma unroll
        for (int tV = 0; tV < 6; ++tV) {
            float4v a = {0.f, 0.f, 0.f, 0.f};
            short8 vf0 = *(const short8*)&lds[VB_ + ((tV * 2 + 0) * 64 + lane) * 8];
            short8 vf1 = *(const short8*)&lds[VB_ + ((tV * 2 + 1) * 64 + lane) * 8];
            a = __builtin_amdgcn_mfma_f32_16x16x32_bf16(pf0, vf0, a, 0, 0, 0);
            a = __builtin_amdgcn_mfma_f32_16x16x32_bf16(pf1, vf1, a, 0, 0, 0);
            ov[tV] = a;
            #pragma unroll
            for (int rg = 0; rg < 4; ++rg)
                lds[Q_ + (rowb + rg) * 104 + tV * 16 + n16] = f2bf(a[rg]);
        }
    }

    // ---------- Phase E: MLP, W1/W2 t-slices staged into LDS (fetched once/window) ----------
    float4v y[6];
    #pragma unroll
    for (int tn = 0; tn < 6; ++tn) y[tn] = (float4v){0.f, 0.f, 0.f, 0.f};
    {
        short8 of[3];
        #pragma unroll
        for (int kc = 0; kc < 3; ++kc)
            of[kc] = *(const short8*)&lds[Q_ + (w * 16 + n16) * 104 + kc * 32 + q * 8];

        for (int t = 0; t < 4; ++t) {
            __syncthreads();                         // WS region free (D done / prev W2 reads done)
            {
                const short* src = wsW1 + t * 9216;
                #pragma unroll
                for (int it = 0; it < 5; ++it) {
                    int cc = tid + it * 256;
                    if (cc < 1152) stage16(src + cc * 8, &lds[WS_ + cc * 8]);
                }
            }
            __syncthreads();                         // W1_t staged
            #pragma unroll
            for (int tn = 0; tn < 6; ++tn) {
                float4v h = {0.f, 0.f, 0.f, 0.f};
                #pragma unroll
                for (int kc = 0; kc < 3; ++kc) {
                    short8 wf = *(const short8*)&lds[WS_ + ((tn * 3 + kc) * 64 + lane) * 8];
                    h = __builtin_amdgcn_mfma_f32_16x16x32_bf16(of[kc], wf, h, 0, 0, 0);
                }
                float bb1 = b1[t * 96 + tn * 16 + n16];
                #pragma unroll
                for (int rg = 0; rg < 4; ++rg)
                    lds[XA_ + (rowb + rg) * 104 + tn * 16 + n16] = f2bf(gelu_sig(h[rg] + bb1));
            }
            short8 hf[3];
            #pragma unroll
            for (int kc = 0; kc < 3; ++kc)           // same-wave H readback (in-order DS)
                hf[kc] = *(const short8*)&lds[XA_ + (w * 16 + n16) * 104 + kc * 32 + q * 8];
            __syncthreads();                         // all W1 reads done
            {
                const short* src = wsW2 + t * 9216;
                #pragma unroll
                for (int it = 0; it < 5; ++it) {
                    int cc = tid + it * 256;
                    if (cc < 1152) stage16(src + cc * 8, &lds[WS_ + cc * 8]);
                }
            }
            __syncthreads();                         // W2_t staged
            #pragma unroll
            for (int tn = 0; tn < 6; ++tn)
                #pragma unroll
                for (int kc = 0; kc < 3; ++kc) {
                    short8 wf = *(const short8*)&lds[WS_ + ((tn * 3 + kc) * 64 + lane) * 8];
                    y[tn] = __builtin_amdgcn_mfma_f32_16x16x32_bf16(hf[kc], wf, y[tn], 0, 0, 0);
                }
        }
    }

    // ---------- Epilogue: out = y + b2 + O ----------
    float b2v[6];
    #pragma unroll
    for (int tn = 0; tn < 6; ++tn) b2v[tn] = b2[tn * 16 + n16];
    #pragma unroll
    for (int rg = 0; rg < 4; ++rg) {
        int r = rowb + rg;
        if (r < 49) {
            int i = r / 7, jj = r - i * 7;
            float* op = out + ((size_t)((bb * 224 + wh * 7 + i) * 224 + ww * 7 + jj)) * 96 + n16;
            #pragma unroll
            for (int tn = 0; tn < 6; ++tn)
                op[tn * 16] = y[tn][rg] + b2v[tn] + ov[tn][rg];
        }
    }
}

extern "C" void kernel_launch(void* const* d_in, const int* in_sizes, int n_in,
                              void* d_out, int out_size, void* d_ws, size_t ws_size,
                              hipStream_t stream) {
    const float* x     = (const float*)d_in[0];
    const float* qkv_w = (const float*)d_in[1];
    const float* ln_w  = (const float*)d_in[2];
    const float* ln_b  = (const float*)d_in[3];
    const float* w1    = (const float*)d_in[4];
    const float* b1    = (const float*)d_in[5];
    const float* w2    = (const float*)d_in[6];
    const float* b2    = (const float*)d_in[7];
    float* out = (float*)d_out;
    short* ws = (short*)d_ws;

    convert_weights<<<396, 256, 0, stream>>>(qkv_w, w1, w2, ws);
    swin_mfma<<<8192, 256, 0, stream>>>(x, ln_w, ln_b, b1, b2, ws, out);
}